// Round 21
// baseline (378.865 us; speedup 1.0000x reference)
//
#include <hip/hip_runtime.h>
#include <cfloat>

// Problem constants
#define B_SZ 8
#define N_SZ 2048
#define D_SZ 512
#define K_SZ 8192
#define M_SZ (B_SZ * N_SZ)  // 16384

#define DECAY_F 0.99f
#define OMD_F ((float)(1.0 - 0.99))
#define EPS_F 1e-5f

// Output layout (flat float offsets, reference return order)
#define OUT1_OFF 8388608   // indices (B*N) as float
#define OUT2_OFF 8404992   // commitment loss (1)
#define OUT3_OFF 8404993   // new_ema_cluster_sizes (K)
#define OUT4_OFF 8413185   // new_ema_codebook (K*D)
#define OUT5_OFF 12607489  // new_embedding (K*D)

typedef unsigned short ushort_t;
typedef unsigned int uint_t;
typedef short bf16x8 __attribute__((ext_vector_type(8)));
typedef float f32x4 __attribute__((ext_vector_type(4)));

// ---- manual RTNE fp32 -> bf16 ----
__device__ inline ushort_t f2bf(float v) {
    union { float f; uint_t u; } x; x.f = v;
    uint_t r = x.u + 0x7FFFu + ((x.u >> 16) & 1u);
    return (ushort_t)(r >> 16);
}

// 16B global -> LDS DMA (linear per-lane dest; vmcnt-counted)
__device__ __forceinline__ void gl16(const void* g, void* l) {
    __builtin_amdgcn_global_load_lds(
        (const __attribute__((address_space(1))) uint_t*)g,
        (__attribute__((address_space(3))) uint_t*)l, 16, 0, 0);
}

// ------- splits: SINGLE bf16 plane, CHUNKED + PRE-SWIZZLED (BK=32) ----
// 64B rows, 4 slots/row. slot phys = kg ^ ((row>>1)&3)  [phase model:
// each 8-lane read phase covers cols {0,4,1,5,2,6,3,7} -> conflict-free].
// e chunk = 128 rows x 64B =  8 KB: (cb,ch) -> (cb*16+ch)*8192
// z chunk = 256 rows x 64B = 16 KB: (zi,ch) -> (zi*16+ch)*16384
// byte[row*64 + ((kg^((row>>1)&3))<<4)] = bf16 of (row, k=ch*32+kg*8..+7)
// k_split_e also emits esq (row == 64 consecutive lanes -> free reduce).
__global__ __launch_bounds__(256) void k_split_e(const float* __restrict__ in,
                                                 ushort_t* __restrict__ ebuf,
                                                 float* __restrict__ esq) {
    int idx = blockIdx.x * 256 + threadIdx.x;
    int row = idx >> 6, o = idx & 63;       // o = k-octet 0..63
    int ch = o >> 2, kg = o & 3;
    const float* src = in + (size_t)row * D_SZ + o * 8;
    float4 a = *(const float4*)src;
    float4 b = *(const float4*)(src + 4);
    float vv[8] = {a.x, a.y, a.z, a.w, b.x, b.y, b.z, b.w};
    ushort_t o1[8];
    float s = 0.f;
#pragma unroll
    for (int j = 0; j < 8; ++j) {
        o1[j] = f2bf(vv[j]);
        s += vv[j] * vv[j];
    }
    int cb = row >> 7, rl = row & 127;
    size_t base = (size_t)(cb * 16 + ch) * 8192 + rl * 64;
    *(uint4*)((unsigned char*)ebuf + base + ((kg ^ ((rl >> 1) & 3)) << 4)) = *(uint4*)o1;
#pragma unroll
    for (int off = 32; off; off >>= 1) s += __shfl_down(s, off);
    if (o == 0) esq[row] = s;
}

__global__ __launch_bounds__(256) void k_split_z(const float* __restrict__ in,
                                                 ushort_t* __restrict__ zbuf) {
    int idx = blockIdx.x * 256 + threadIdx.x;
    int row = idx >> 6, o = idx & 63;
    int ch = o >> 2, kg = o & 3;
    const float* src = in + (size_t)row * D_SZ + o * 8;
    float4 a = *(const float4*)src;
    float4 b = *(const float4*)(src + 4);
    float vv[8] = {a.x, a.y, a.z, a.w, b.x, b.y, b.z, b.w};
    ushort_t o1[8];
#pragma unroll
    for (int j = 0; j < 8; ++j) o1[j] = f2bf(vv[j]);
    int zi = row >> 8, rl = row & 255;      // 256-row z chunks
    size_t base = (size_t)(zi * 16 + ch) * 16384 + rl * 64;
    *(uint4*)((unsigned char*)zbuf + base + ((kg ^ ((rl >> 1) & 3)) << 4)) = *(uint4*)o1;
}

// -------- fused init (out3/out4 scale) + copy (out0 = z) -------------
__global__ __launch_bounds__(256) void k_initcopy(const float* __restrict__ cb,
                                                  const float* __restrict__ sizes,
                                                  const float* __restrict__ z,
                                                  float* __restrict__ out3,
                                                  float* __restrict__ out4,
                                                  float* __restrict__ out0) {
    int b = blockIdx.x;
    if (b < 16384) {
        int i = b * 256 + threadIdx.x;
        out4[i] = cb[i] * DECAY_F;
        if (i < K_SZ) out3[i] = sizes[i] * DECAY_F;
    } else {
        int i = (b - 16384) * 256 + threadIdx.x;
        ((float4*)out0)[i] = ((const float4*)z)[i];
    }
}

__global__ __launch_bounds__(256) void k_scatter(const float* __restrict__ z,
                                                 const float* __restrict__ e,
                                                 const int* __restrict__ nearest,
                                                 float* __restrict__ out3,
                                                 float* __restrict__ out4,
                                                 float* __restrict__ lossAcc) {
    const int tid = threadIdx.x;
    float lp = 0.f;
    const int base_row = blockIdx.x * 8;
#pragma unroll
    for (int r = 0; r < 8; ++r) {
        int row = base_row + r;
        int n = nearest[row];
        float2 zv = ((const float2*)(z + (size_t)row * D_SZ))[tid];
        float2 ev = ((const float2*)(e + (size_t)n * D_SZ))[tid];
        float* o4 = out4 + (size_t)n * D_SZ + tid * 2;
        atomicAdd(o4, OMD_F * zv.x);
        atomicAdd(o4 + 1, OMD_F * zv.y);
        float dx = zv.x - ev.x, dy = zv.y - ev.y;
        lp += dx * dx + dy * dy;
        if (tid == 0) atomicAdd(out3 + n, OMD_F);
    }
#pragma unroll
    for (int off = 32; off; off >>= 1) lp += __shfl_down(lp, off);
    __shared__ float red[4];
    if ((tid & 63) == 0) red[tid >> 6] = lp;
    __syncthreads();
    if (tid == 0) atomicAdd(lossAcc, red[0] + red[1] + red[2] + red[3]);
}

__global__ __launch_bounds__(256) void k_final(const float* __restrict__ out3,
                                               const float* __restrict__ out4,
                                               float* __restrict__ out5,
                                               const float* __restrict__ lossAcc,
                                               float* __restrict__ out2) {
    int i = blockIdx.x * 256 + threadIdx.x;
    out5[i] = out4[i] / (out3[i >> 9] + EPS_F);
    if (i == 0) out2[0] = 0.25f * lossAcc[0] / 8388608.0f;
}

// ---------------- pass 1: single-plane bf16 MFMA + per-list top2 -----
// 128c x 256z tile, BK=32 (16 chunks), 512 thr = 8 waves (2mw x 4nw),
// wave tile 64c x 64z (acc[4][4]): 8 ds_read_b128 : 16 MFMA per wave
// per chunk (ratio 2.0). Buffers 24 KB; dbuf 48 KB used; LDS DECLARED
// 72 KB: 2 blocks x 72 = 144 KB < 160 KB even with runtime reservation
// -> 2 blocks/CU = 16 waves = 4 waves/SIMD. (R20 declared 80 KB: 2x80 =
// exactly 160 KB did NOT fit -> 1 block, occupancy 23.8%, MfmaUtil 24%.
// R20 also proved this body compiles spill-free at 72 VGPR.)
// Counted vmcnt (T4): ISSUE(t+1) [3 loads]; vmcnt(3); barrier;
// compute(t); barrier — never drain to 0 in the loop (R18-verified).
// A/B frag (16x16x32): lane -> row=lr (lane&15), k-octet = g(lane>>4).
// C/D: col=lane&15 (z), row=g*4+reg (code)  [m89/m91].
__global__ __launch_bounds__(512) void k_pass1(const ushort_t* __restrict__ ebuf,
                                               const ushort_t* __restrict__ zbuf,
                                               const float* __restrict__ esq,
                                               float* __restrict__ candD,
                                               ushort_t* __restrict__ candI) {
    // 2 x 24 KB used; declared 72 KB to pin the 2-blocks/CU tier.
    __shared__ __align__(16) unsigned char ldsb[73728];

    const int tid = threadIdx.x;
    const int lane = tid & 63;
    const int wv = tid >> 6;            // 0..7
    const int mw = wv >> 2;             // 0..1 (code wave-half)
    const int nw = wv & 3;              // 0..3 (z wave-quarter of 256)
    const int lr = lane & 15;           // frag row
    const int g = lane >> 4;            // k-octet / D row-group

    // XCD pinning: blockIdx&7 = XCD = cb>>3 -> each XCD owns a 1024-code
    // e-slice (1 MB single-plane) resident in its L2.
    const int xcd = blockIdx.x & 7;
    const int cbl = (blockIdx.x >> 3) & 7;
    const int zi = blockIdx.x >> 6;     // 0..63 (256-z tiles)
    const int cb = xcd * 8 + cbl;       // 0..63

    const unsigned char* esrc = (const unsigned char*)ebuf + (size_t)cb * 131072 + tid * 16;
    const unsigned char* zsrc = (const unsigned char*)zbuf + (size_t)zi * 262144 + tid * 16;

#define ISSUE(c, b) do {                                                \
        const unsigned char* ep_ = esrc + (c) * 8192;                   \
        const unsigned char* zp_ = zsrc + (c) * 16384;                  \
        unsigned char* el_ = ldsb + (b) * 24576 + tid * 16;             \
        unsigned char* zl_ = el_ + 8192;                                \
        gl16(ep_, el_);                                                 \
        gl16(zp_, zl_); gl16(zp_ + 8192, zl_ + 8192);                   \
    } while (0)

    f32x4 acc[4][4];
#pragma unroll
    for (int mf = 0; mf < 4; ++mf)
#pragma unroll
        for (int nf = 0; nf < 4; ++nf)
            acc[mf][nf] = (f32x4){0.f, 0.f, 0.f, 0.f};

    // prologue: chunk 0 -> buf 0 (wait happens inside the loop)
    ISSUE(0, 0);

    int cur = 0;
    for (int ch = 0; ch < 16; ++ch) {
        // issue-early: next chunk -> other buffer, then wait ONLY for
        // chunk ch's 3 loads (the 3 newest outstanding are ch+1's).
        if (ch < 15) {
            if (cur) ISSUE(ch + 1, 0); else ISSUE(ch + 1, 1);
            asm volatile("s_waitcnt vmcnt(3)" ::: "memory");
        } else {
            asm volatile("s_waitcnt vmcnt(0)" ::: "memory");
        }
        __builtin_amdgcn_s_barrier();   // all waves' chunk-ch loads landed
        asm volatile("" ::: "memory");

        const unsigned char* eb = ldsb + cur * 24576;
        const unsigned char* zp = eb + 8192;

        bf16x8 zf[4];
#pragma unroll
        for (int nf = 0; nf < 4; ++nf) {
            int row = nw * 64 + nf * 16 + lr;
            int sl = g ^ ((row >> 1) & 3);
            zf[nf] = *(const bf16x8*)(zp + row * 64 + (sl << 4));
        }
#pragma unroll
        for (int mf = 0; mf < 4; ++mf) {
            int row = mw * 64 + mf * 16 + lr;
            int sl = g ^ ((row >> 1) & 3);
            bf16x8 ef = *(const bf16x8*)(eb + row * 64 + (sl << 4));
#pragma unroll
            for (int nf = 0; nf < 4; ++nf)
                acc[mf][nf] = __builtin_amdgcn_mfma_f32_16x16x32_bf16(ef, zf[nf], acc[mf][nf], 0, 0, 0);
        }
        // all waves done reading buf before next ISSUE overwrites it
        __builtin_amdgcn_s_barrier();
        asm volatile("" ::: "memory");
        cur ^= 1;
    }
#undef ISSUE

    // epilogue: dist = esq - 2*dot; per-zrow top2 over this wave's 64 codes
    float b1[4], b2[4];
    int i1[4], i2[4];
#pragma unroll
    for (int nf = 0; nf < 4; ++nf) {
        b1[nf] = FLT_MAX; b2[nf] = FLT_MAX;
        i1[nf] = 0x7fffffff; i2[nf] = 0x7fffffff;
    }
    const int code0 = cb * 128 + mw * 64;
#pragma unroll
    for (int mf = 0; mf < 4; ++mf)
#pragma unroll
        for (int r = 0; r < 4; ++r) {
            int code = code0 + mf * 16 + g * 4 + r;
            float eq = esq[code];
#pragma unroll
            for (int nf = 0; nf < 4; ++nf) {
                float d = fmaf(-2.f, acc[mf][nf][r], eq);
                if (d < b1[nf]) {
                    b2[nf] = b1[nf]; i2[nf] = i1[nf];
                    b1[nf] = d; i1[nf] = code;
                } else if (d < b2[nf]) {
                    b2[nf] = d; i2[nf] = code;
                }
            }
        }

    // merge top2 across the 4 k-groups holding the same zrow (xor 16, 32)
#pragma unroll
    for (int off = 16; off <= 32; off <<= 1) {
#pragma unroll
        for (int nf = 0; nf < 4; ++nf) {
            float ob1 = __shfl_xor(b1[nf], off); int oi1 = __shfl_xor(i1[nf], off);
            float ob2 = __shfl_xor(b2[nf], off); int oi2 = __shfl_xor(i2[nf], off);
            bool tA = (b1[nf] < ob1) || (b1[nf] == ob1 && i1[nf] <= oi1);
            float n1 = tA ? b1[nf] : ob1; int ni1 = tA ? i1[nf] : oi1;
            float ca = tA ? b2[nf] : ob2; int cia = tA ? i2[nf] : oi2;
            float cbv = tA ? ob1 : b1[nf]; int cib = tA ? oi1 : i1[nf];
            bool t2 = (ca < cbv) || (ca == cbv && cia <= cib);
            b1[nf] = n1; i1[nf] = ni1;
            b2[nf] = t2 ? ca : cbv; i2[nf] = t2 ? cia : cib;
        }
    }

    // cross-wave merge (mw=0 vs mw=1 cover the same 256 zrows) via LDS
    __syncthreads();
    float* mD = (float*)ldsb;          // [256][2] floats (2 KB)
    int* mI = (int*)(ldsb + 2048);     // [256][2] ints   (2 KB)
    if (mw == 1 && g == 0) {
#pragma unroll
        for (int nf = 0; nf < 4; ++nf) {
            int zr = nw * 64 + nf * 16 + lr;
            mD[zr * 2] = b1[nf]; mD[zr * 2 + 1] = b2[nf];
            mI[zr * 2] = i1[nf]; mI[zr * 2 + 1] = i2[nf];
        }
    }
    __syncthreads();
    if (mw == 0 && g == 0) {
#pragma unroll
        for (int nf = 0; nf < 4; ++nf) {
            int zr = nw * 64 + nf * 16 + lr;
            float ob1 = mD[zr * 2], ob2 = mD[zr * 2 + 1];
            int oi1 = mI[zr * 2], oi2 = mI[zr * 2 + 1];
            bool tA = (b1[nf] < ob1) || (b1[nf] == ob1 && i1[nf] <= oi1);
            float n1 = tA ? b1[nf] : ob1; int ni1 = tA ? i1[nf] : oi1;
            float ca = tA ? b2[nf] : ob2; int cia = tA ? i2[nf] : oi2;
            float cbv = tA ? ob1 : b1[nf]; int cib = tA ? oi1 : i1[nf];
            bool t2 = (ca < cbv) || (ca == cbv && cia <= cib);
            float n2 = t2 ? ca : cbv; int ni2 = t2 ? cia : cib;
            int row = zi * 256 + zr;
            size_t base = (size_t)row * 128 + cb * 2;
            candD[base] = n1; candD[base + 1] = n2;
            candI[base] = (ushort_t)ni1; candI[base + 1] = (ushort_t)ni2;
        }
    }
}

// ---------------- refine: exact fp32 re-rank of merged top-8 ---------
// 128 candidates/row (top-2 x 64 lists); extract 8 approx-minima, exact
// fp32 re-rank (same expression as verified R5-R18 refine).
__global__ __launch_bounds__(256) void k_refine(const float* __restrict__ z,
                                                const float* __restrict__ e,
                                                const float* __restrict__ esq,
                                                const float* __restrict__ candD,
                                                const ushort_t* __restrict__ candI,
                                                int* __restrict__ nearest,
                                                float* __restrict__ out1) {
    const int lane = threadIdx.x & 63;
    const int row = blockIdx.x * 4 + (threadIdx.x >> 6);

    const float4* zr = (const float4*)(z + (size_t)row * D_SZ + lane * 8);
    float4 za = zr[0], zb = zr[1];
    float zsq = za.x * za.x + za.y * za.y + za.z * za.z + za.w * za.w +
                zb.x * zb.x + zb.y * zb.y + zb.z * zb.z + zb.w * zb.w;
#pragma unroll
    for (int off = 32; off; off >>= 1) zsq += __shfl_xor(zsq, off);

    float da = candD[(size_t)row * 128 + lane];
    int ia = candI[(size_t)row * 128 + lane];
    float db = candD[(size_t)row * 128 + 64 + lane];
    int ib = candI[(size_t)row * 128 + 64 + lane];

    float best = FLT_MAX;
    int bidx = 0x7fffffff;
#pragma unroll
    for (int c = 0; c < 8; ++c) {
        bool pa = (da < db) || (da == db && ia < ib);
        float md = pa ? da : db;
        int mi = pa ? ia : ib;
#pragma unroll
        for (int off = 32; off; off >>= 1) {
            float od = __shfl_xor(md, off); int oi = __shfl_xor(mi, off);
            if (od < md || (od == md && oi < mi)) { md = od; mi = oi; }
        }
        if (ia == mi) da = FLT_MAX;  // codes unique across all 128 cands
        if (ib == mi) db = FLT_MAX;
        // exact fp32 distance for candidate mi
        const float4* er = (const float4*)(e + (size_t)mi * D_SZ + lane * 8);
        float4 ea = er[0], eb = er[1];
        float dot = za.x * ea.x + za.y * ea.y + za.z * ea.z + za.w * ea.w +
                    zb.x * eb.x + zb.y * eb.y + zb.z * eb.z + zb.w * eb.w;
#pragma unroll
        for (int off = 32; off; off >>= 1) dot += __shfl_xor(dot, off);
        float dex = (zsq - 2.f * dot) + esq[mi];
        if (dex < best || (dex == best && mi < bidx)) { best = dex; bidx = mi; }
    }
    if (lane == 0) {
        nearest[row] = bidx;
        out1[row] = (float)bidx;
    }
}

extern "C" void kernel_launch(void* const* d_in, const int* in_sizes, int n_in,
                              void* d_out, int out_size, void* d_ws, size_t ws_size,
                              hipStream_t stream) {
    const float* z = (const float*)d_in[0];
    const float* ew = (const float*)d_in[1];
    const float* sizes = (const float*)d_in[2];
    const float* cb = (const float*)d_in[3];

    float* out = (float*)d_out;
    float* out0 = out;
    float* out1 = out + OUT1_OFF;
    float* out2 = out + OUT2_OFF;
    float* out3 = out + OUT3_OFF;
    float* out4 = out + OUT4_OFF;
    float* out5 = out + OUT5_OFF;

    // ws scratch (small)
    int* nearest = (int*)d_ws;
    float* esq = (float*)d_ws + M_SZ;
    float* lossAcc = (float*)d_ws + M_SZ + K_SZ;

    // chunked/pre-swizzled single-plane buffers inside d_out (consumed
    // before the real outputs overwrite them):
    //   zbuf: out0 region, 16 MB (64 zi x 16 ch x 16 KB)
    //   ebuf: out4+12B,     8 MB (64 cb x 16 ch x  8 KB)
    //   candD f32 8 MB, candI ushort 4 MB after ebuf (fits out4+out5)
    ushort_t* zbuf = (ushort_t*)out0;
    unsigned char* s4 = (unsigned char*)out4 + 12;
    ushort_t* ebuf = (ushort_t*)s4;
    float* candD = (float*)(s4 + 8388608);
    ushort_t* candI = (ushort_t*)(s4 + 8388608 + 8388608);

    hipMemsetAsync(lossAcc, 0, sizeof(float), stream);

    k_split_z<<<(M_SZ * 64) / 256, 256, 0, stream>>>(z, zbuf);
    k_split_e<<<(K_SZ * 64) / 256, 256, 0, stream>>>(ew, ebuf, esq);

    k_pass1<<<4096, 512, 0, stream>>>(ebuf, zbuf, esq, candD, candI);
    k_refine<<<M_SZ / 4, 256, 0, stream>>>(z, ew, esq, candD, candI, nearest, out1);

    // now safe to overwrite scratch regions with real outputs
    k_initcopy<<<16384 + 8192, 256, 0, stream>>>(cb, sizes, z, out3, out4, out0);
    k_scatter<<<M_SZ / 8, 256, 0, stream>>>(z, ew, nearest, out3, out4, lossAcc);
    k_final<<<(K_SZ * D_SZ) / 256, 256, 0, stream>>>(out3, out4, out5, lossAcc, out2);
}

// Round 22
// 377.735 us; speedup vs baseline: 1.0030x; 1.0030x over previous
//
#include <hip/hip_runtime.h>
#include <cfloat>

// Problem constants
#define B_SZ 8
#define N_SZ 2048
#define D_SZ 512
#define K_SZ 8192
#define M_SZ (B_SZ * N_SZ)  // 16384

#define DECAY_F 0.99f
#define OMD_F ((float)(1.0 - 0.99))
#define EPS_F 1e-5f

// Output layout (flat float offsets, reference return order)
#define OUT1_OFF 8388608   // indices (B*N) as float
#define OUT2_OFF 8404992   // commitment loss (1)
#define OUT3_OFF 8404993   // new_ema_cluster_sizes (K)
#define OUT4_OFF 8413185   // new_ema_codebook (K*D)
#define OUT5_OFF 12607489  // new_embedding (K*D)

typedef unsigned short ushort_t;
typedef unsigned int uint_t;
typedef short bf16x8 __attribute__((ext_vector_type(8)));
typedef float f32x4 __attribute__((ext_vector_type(4)));

// ---- manual RTNE fp32 -> bf16 ----
__device__ inline ushort_t f2bf(float v) {
    union { float f; uint_t u; } x; x.f = v;
    uint_t r = x.u + 0x7FFFu + ((x.u >> 16) & 1u);
    return (ushort_t)(r >> 16);
}

// 16B global -> LDS DMA (linear per-lane dest; vmcnt-counted)
__device__ __forceinline__ void gl16(const void* g, void* l) {
    __builtin_amdgcn_global_load_lds(
        (const __attribute__((address_space(1))) uint_t*)g,
        (__attribute__((address_space(3))) uint_t*)l, 16, 0, 0);
}

// ------- splits: SINGLE bf16 plane, CHUNKED + PRE-SWIZZLED (BK=32) ----
// 64B rows, 4 slots/row. slot phys = kg ^ ((row>>1)&3)  [phase model:
// each 8-lane read phase covers cols {0,4,1,5,2,6,3,7} -> conflict-free].
// e chunk = 128 rows x 64B =  8 KB: (cb,ch) -> (cb*16+ch)*8192
// z chunk = 256 rows x 64B = 16 KB: (zi,ch) -> (zi*16+ch)*16384
// byte[row*64 + ((kg^((row>>1)&3))<<4)] = bf16 of (row, k=ch*32+kg*8..+7)
// k_split_e also emits esq (row == 64 consecutive lanes -> free reduce).
__global__ __launch_bounds__(256) void k_split_e(const float* __restrict__ in,
                                                 ushort_t* __restrict__ ebuf,
                                                 float* __restrict__ esq) {
    int idx = blockIdx.x * 256 + threadIdx.x;
    int row = idx >> 6, o = idx & 63;       // o = k-octet 0..63
    int ch = o >> 2, kg = o & 3;
    const float* src = in + (size_t)row * D_SZ + o * 8;
    float4 a = *(const float4*)src;
    float4 b = *(const float4*)(src + 4);
    float vv[8] = {a.x, a.y, a.z, a.w, b.x, b.y, b.z, b.w};
    ushort_t o1[8];
    float s = 0.f;
#pragma unroll
    for (int j = 0; j < 8; ++j) {
        o1[j] = f2bf(vv[j]);
        s += vv[j] * vv[j];
    }
    int cb = row >> 7, rl = row & 127;
    size_t base = (size_t)(cb * 16 + ch) * 8192 + rl * 64;
    *(uint4*)((unsigned char*)ebuf + base + ((kg ^ ((rl >> 1) & 3)) << 4)) = *(uint4*)o1;
#pragma unroll
    for (int off = 32; off; off >>= 1) s += __shfl_down(s, off);
    if (o == 0) esq[row] = s;
}

__global__ __launch_bounds__(256) void k_split_z(const float* __restrict__ in,
                                                 ushort_t* __restrict__ zbuf) {
    int idx = blockIdx.x * 256 + threadIdx.x;
    int row = idx >> 6, o = idx & 63;
    int ch = o >> 2, kg = o & 3;
    const float* src = in + (size_t)row * D_SZ + o * 8;
    float4 a = *(const float4*)src;
    float4 b = *(const float4*)(src + 4);
    float vv[8] = {a.x, a.y, a.z, a.w, b.x, b.y, b.z, b.w};
    ushort_t o1[8];
#pragma unroll
    for (int j = 0; j < 8; ++j) o1[j] = f2bf(vv[j]);
    int zi = row >> 8, rl = row & 255;      // 256-row z chunks
    size_t base = (size_t)(zi * 16 + ch) * 16384 + rl * 64;
    *(uint4*)((unsigned char*)zbuf + base + ((kg ^ ((rl >> 1) & 3)) << 4)) = *(uint4*)o1;
}

// -------- fused init (out3/out4 scale) + copy (out0 = z) -------------
__global__ __launch_bounds__(256) void k_initcopy(const float* __restrict__ cb,
                                                  const float* __restrict__ sizes,
                                                  const float* __restrict__ z,
                                                  float* __restrict__ out3,
                                                  float* __restrict__ out4,
                                                  float* __restrict__ out0) {
    int b = blockIdx.x;
    if (b < 16384) {
        int i = b * 256 + threadIdx.x;
        out4[i] = cb[i] * DECAY_F;
        if (i < K_SZ) out3[i] = sizes[i] * DECAY_F;
    } else {
        int i = (b - 16384) * 256 + threadIdx.x;
        ((float4*)out0)[i] = ((const float4*)z)[i];
    }
}

__global__ __launch_bounds__(256) void k_scatter(const float* __restrict__ z,
                                                 const float* __restrict__ e,
                                                 const int* __restrict__ nearest,
                                                 float* __restrict__ out3,
                                                 float* __restrict__ out4,
                                                 float* __restrict__ lossAcc) {
    const int tid = threadIdx.x;
    float lp = 0.f;
    const int base_row = blockIdx.x * 8;
#pragma unroll
    for (int r = 0; r < 8; ++r) {
        int row = base_row + r;
        int n = nearest[row];
        float2 zv = ((const float2*)(z + (size_t)row * D_SZ))[tid];
        float2 ev = ((const float2*)(e + (size_t)n * D_SZ))[tid];
        float* o4 = out4 + (size_t)n * D_SZ + tid * 2;
        atomicAdd(o4, OMD_F * zv.x);
        atomicAdd(o4 + 1, OMD_F * zv.y);
        float dx = zv.x - ev.x, dy = zv.y - ev.y;
        lp += dx * dx + dy * dy;
        if (tid == 0) atomicAdd(out3 + n, OMD_F);
    }
#pragma unroll
    for (int off = 32; off; off >>= 1) lp += __shfl_down(lp, off);
    __shared__ float red[4];
    if ((tid & 63) == 0) red[tid >> 6] = lp;
    __syncthreads();
    if (tid == 0) atomicAdd(lossAcc, red[0] + red[1] + red[2] + red[3]);
}

__global__ __launch_bounds__(256) void k_final(const float* __restrict__ out3,
                                               const float* __restrict__ out4,
                                               float* __restrict__ out5,
                                               const float* __restrict__ lossAcc,
                                               float* __restrict__ out2) {
    int i = blockIdx.x * 256 + threadIdx.x;
    out5[i] = out4[i] / (out3[i >> 9] + EPS_F);
    if (i == 0) out2[0] = 0.25f * lossAcc[0] / 8388608.0f;
}

// ---------------- pass 1: single-plane bf16 MFMA + per-list top2 -----
// 128c x 256z tile, BK=32 (16 chunks), 512 thr = 8 waves (2mw x 4nw),
// wave tile 64c x 64z (acc[4][4]): 8 ds_read_b128 : 16 MFMA per wave
// per chunk (ratio 2.0). LDS = TRUE dbuf size 48 KB.
// Occupancy model (session-measured): usable LDS co-residency pool is
// ~128 KB, not 160 (64 KB -> 2 blocks [R13/R18]; 72/80 KB -> 1 block
// [R20/R21]). 2 x 48 = 96 <= 128 -> 2 blocks/CU = 4 waves/SIMD, the
// regime where the chunk pipeline overlaps. Body compiles at 72 VGPR
// (R20/R21-measured), under even a 3-block/85-VGPR target -> no spill.
// Counted vmcnt (T4): ISSUE(t+1) [3 loads]; vmcnt(3); barrier;
// compute(t); barrier — never drain to 0 in the loop (R18-verified).
// A/B frag (16x16x32): lane -> row=lr (lane&15), k-octet = g(lane>>4).
// C/D: col=lane&15 (z), row=g*4+reg (code)  [m89/m91].
__global__ __launch_bounds__(512) void k_pass1(const ushort_t* __restrict__ ebuf,
                                               const ushort_t* __restrict__ zbuf,
                                               const float* __restrict__ esq,
                                               float* __restrict__ candD,
                                               ushort_t* __restrict__ candI) {
    __shared__ __align__(16) unsigned char ldsb[49152];  // 2 x 24 KB

    const int tid = threadIdx.x;
    const int lane = tid & 63;
    const int wv = tid >> 6;            // 0..7
    const int mw = wv >> 2;             // 0..1 (code wave-half)
    const int nw = wv & 3;              // 0..3 (z wave-quarter of 256)
    const int lr = lane & 15;           // frag row
    const int g = lane >> 4;            // k-octet / D row-group

    // XCD pinning: blockIdx&7 = XCD = cb>>3 -> each XCD owns a 1024-code
    // e-slice (1 MB single-plane) resident in its L2.
    const int xcd = blockIdx.x & 7;
    const int cbl = (blockIdx.x >> 3) & 7;
    const int zi = blockIdx.x >> 6;     // 0..63 (256-z tiles)
    const int cb = xcd * 8 + cbl;       // 0..63

    const unsigned char* esrc = (const unsigned char*)ebuf + (size_t)cb * 131072 + tid * 16;
    const unsigned char* zsrc = (const unsigned char*)zbuf + (size_t)zi * 262144 + tid * 16;

#define ISSUE(c, b) do {                                                \
        const unsigned char* ep_ = esrc + (c) * 8192;                   \
        const unsigned char* zp_ = zsrc + (c) * 16384;                  \
        unsigned char* el_ = ldsb + (b) * 24576 + tid * 16;             \
        unsigned char* zl_ = el_ + 8192;                                \
        gl16(ep_, el_);                                                 \
        gl16(zp_, zl_); gl16(zp_ + 8192, zl_ + 8192);                   \
    } while (0)

    f32x4 acc[4][4];
#pragma unroll
    for (int mf = 0; mf < 4; ++mf)
#pragma unroll
        for (int nf = 0; nf < 4; ++nf)
            acc[mf][nf] = (f32x4){0.f, 0.f, 0.f, 0.f};

    // prologue: chunk 0 -> buf 0 (wait happens inside the loop)
    ISSUE(0, 0);

    int cur = 0;
    for (int ch = 0; ch < 16; ++ch) {
        // issue-early: next chunk -> other buffer, then wait ONLY for
        // chunk ch's 3 loads (the 3 newest outstanding are ch+1's).
        if (ch < 15) {
            if (cur) ISSUE(ch + 1, 0); else ISSUE(ch + 1, 1);
            asm volatile("s_waitcnt vmcnt(3)" ::: "memory");
        } else {
            asm volatile("s_waitcnt vmcnt(0)" ::: "memory");
        }
        __builtin_amdgcn_s_barrier();   // all waves' chunk-ch loads landed
        asm volatile("" ::: "memory");

        const unsigned char* eb = ldsb + cur * 24576;
        const unsigned char* zp = eb + 8192;

        bf16x8 zf[4];
#pragma unroll
        for (int nf = 0; nf < 4; ++nf) {
            int row = nw * 64 + nf * 16 + lr;
            int sl = g ^ ((row >> 1) & 3);
            zf[nf] = *(const bf16x8*)(zp + row * 64 + (sl << 4));
        }
#pragma unroll
        for (int mf = 0; mf < 4; ++mf) {
            int row = mw * 64 + mf * 16 + lr;
            int sl = g ^ ((row >> 1) & 3);
            bf16x8 ef = *(const bf16x8*)(eb + row * 64 + (sl << 4));
#pragma unroll
            for (int nf = 0; nf < 4; ++nf)
                acc[mf][nf] = __builtin_amdgcn_mfma_f32_16x16x32_bf16(ef, zf[nf], acc[mf][nf], 0, 0, 0);
        }
        // all waves done reading buf before next ISSUE overwrites it
        __builtin_amdgcn_s_barrier();
        asm volatile("" ::: "memory");
        cur ^= 1;
    }
#undef ISSUE

    // epilogue: dist = esq - 2*dot; per-zrow top2 over this wave's 64 codes
    float b1[4], b2[4];
    int i1[4], i2[4];
#pragma unroll
    for (int nf = 0; nf < 4; ++nf) {
        b1[nf] = FLT_MAX; b2[nf] = FLT_MAX;
        i1[nf] = 0x7fffffff; i2[nf] = 0x7fffffff;
    }
    const int code0 = cb * 128 + mw * 64;
#pragma unroll
    for (int mf = 0; mf < 4; ++mf)
#pragma unroll
        for (int r = 0; r < 4; ++r) {
            int code = code0 + mf * 16 + g * 4 + r;
            float eq = esq[code];
#pragma unroll
            for (int nf = 0; nf < 4; ++nf) {
                float d = fmaf(-2.f, acc[mf][nf][r], eq);
                if (d < b1[nf]) {
                    b2[nf] = b1[nf]; i2[nf] = i1[nf];
                    b1[nf] = d; i1[nf] = code;
                } else if (d < b2[nf]) {
                    b2[nf] = d; i2[nf] = code;
                }
            }
        }

    // merge top2 across the 4 k-groups holding the same zrow (xor 16, 32)
#pragma unroll
    for (int off = 16; off <= 32; off <<= 1) {
#pragma unroll
        for (int nf = 0; nf < 4; ++nf) {
            float ob1 = __shfl_xor(b1[nf], off); int oi1 = __shfl_xor(i1[nf], off);
            float ob2 = __shfl_xor(b2[nf], off); int oi2 = __shfl_xor(i2[nf], off);
            bool tA = (b1[nf] < ob1) || (b1[nf] == ob1 && i1[nf] <= oi1);
            float n1 = tA ? b1[nf] : ob1; int ni1 = tA ? i1[nf] : oi1;
            float ca = tA ? b2[nf] : ob2; int cia = tA ? i2[nf] : oi2;
            float cbv = tA ? ob1 : b1[nf]; int cib = tA ? oi1 : i1[nf];
            bool t2 = (ca < cbv) || (ca == cbv && cia <= cib);
            b1[nf] = n1; i1[nf] = ni1;
            b2[nf] = t2 ? ca : cbv; i2[nf] = t2 ? cia : cib;
        }
    }

    // cross-wave merge (mw=0 vs mw=1 cover the same 256 zrows) via LDS
    __syncthreads();
    float* mD = (float*)ldsb;          // [256][2] floats (2 KB)
    int* mI = (int*)(ldsb + 2048);     // [256][2] ints   (2 KB)
    if (mw == 1 && g == 0) {
#pragma unroll
        for (int nf = 0; nf < 4; ++nf) {
            int zr = nw * 64 + nf * 16 + lr;
            mD[zr * 2] = b1[nf]; mD[zr * 2 + 1] = b2[nf];
            mI[zr * 2] = i1[nf]; mI[zr * 2 + 1] = i2[nf];
        }
    }
    __syncthreads();
    if (mw == 0 && g == 0) {
#pragma unroll
        for (int nf = 0; nf < 4; ++nf) {
            int zr = nw * 64 + nf * 16 + lr;
            float ob1 = mD[zr * 2], ob2 = mD[zr * 2 + 1];
            int oi1 = mI[zr * 2], oi2 = mI[zr * 2 + 1];
            bool tA = (b1[nf] < ob1) || (b1[nf] == ob1 && i1[nf] <= oi1);
            float n1 = tA ? b1[nf] : ob1; int ni1 = tA ? i1[nf] : oi1;
            float ca = tA ? b2[nf] : ob2; int cia = tA ? i2[nf] : oi2;
            float cbv = tA ? ob1 : b1[nf]; int cib = tA ? oi1 : i1[nf];
            bool t2 = (ca < cbv) || (ca == cbv && cia <= cib);
            float n2 = t2 ? ca : cbv; int ni2 = t2 ? cia : cib;
            int row = zi * 256 + zr;
            size_t base = (size_t)row * 128 + cb * 2;
            candD[base] = n1; candD[base + 1] = n2;
            candI[base] = (ushort_t)ni1; candI[base + 1] = (ushort_t)ni2;
        }
    }
}

// ---------------- refine: exact fp32 re-rank of merged top-8 ---------
// 128 candidates/row (top-2 x 64 lists); extract 8 approx-minima, exact
// fp32 re-rank (same expression as verified R5-R18 refine).
__global__ __launch_bounds__(256) void k_refine(const float* __restrict__ z,
                                                const float* __restrict__ e,
                                                const float* __restrict__ esq,
                                                const float* __restrict__ candD,
                                                const ushort_t* __restrict__ candI,
                                                int* __restrict__ nearest,
                                                float* __restrict__ out1) {
    const int lane = threadIdx.x & 63;
    const int row = blockIdx.x * 4 + (threadIdx.x >> 6);

    const float4* zr = (const float4*)(z + (size_t)row * D_SZ + lane * 8);
    float4 za = zr[0], zb = zr[1];
    float zsq = za.x * za.x + za.y * za.y + za.z * za.z + za.w * za.w +
                zb.x * zb.x + zb.y * zb.y + zb.z * zb.z + zb.w * zb.w;
#pragma unroll
    for (int off = 32; off; off >>= 1) zsq += __shfl_xor(zsq, off);

    float da = candD[(size_t)row * 128 + lane];
    int ia = candI[(size_t)row * 128 + lane];
    float db = candD[(size_t)row * 128 + 64 + lane];
    int ib = candI[(size_t)row * 128 + 64 + lane];

    float best = FLT_MAX;
    int bidx = 0x7fffffff;
#pragma unroll
    for (int c = 0; c < 8; ++c) {
        bool pa = (da < db) || (da == db && ia < ib);
        float md = pa ? da : db;
        int mi = pa ? ia : ib;
#pragma unroll
        for (int off = 32; off; off >>= 1) {
            float od = __shfl_xor(md, off); int oi = __shfl_xor(mi, off);
            if (od < md || (od == md && oi < mi)) { md = od; mi = oi; }
        }
        if (ia == mi) da = FLT_MAX;  // codes unique across all 128 cands
        if (ib == mi) db = FLT_MAX;
        // exact fp32 distance for candidate mi
        const float4* er = (const float4*)(e + (size_t)mi * D_SZ + lane * 8);
        float4 ea = er[0], eb = er[1];
        float dot = za.x * ea.x + za.y * ea.y + za.z * ea.z + za.w * ea.w +
                    zb.x * eb.x + zb.y * eb.y + zb.z * eb.z + zb.w * eb.w;
#pragma unroll
        for (int off = 32; off; off >>= 1) dot += __shfl_xor(dot, off);
        float dex = (zsq - 2.f * dot) + esq[mi];
        if (dex < best || (dex == best && mi < bidx)) { best = dex; bidx = mi; }
    }
    if (lane == 0) {
        nearest[row] = bidx;
        out1[row] = (float)bidx;
    }
}

extern "C" void kernel_launch(void* const* d_in, const int* in_sizes, int n_in,
                              void* d_out, int out_size, void* d_ws, size_t ws_size,
                              hipStream_t stream) {
    const float* z = (const float*)d_in[0];
    const float* ew = (const float*)d_in[1];
    const float* sizes = (const float*)d_in[2];
    const float* cb = (const float*)d_in[3];

    float* out = (float*)d_out;
    float* out0 = out;
    float* out1 = out + OUT1_OFF;
    float* out2 = out + OUT2_OFF;
    float* out3 = out + OUT3_OFF;
    float* out4 = out + OUT4_OFF;
    float* out5 = out + OUT5_OFF;

    // ws scratch (small)
    int* nearest = (int*)d_ws;
    float* esq = (float*)d_ws + M_SZ;
    float* lossAcc = (float*)d_ws + M_SZ + K_SZ;

    // chunked/pre-swizzled single-plane buffers inside d_out (consumed
    // before the real outputs overwrite them):
    //   zbuf: out0 region, 16 MB (64 zi x 16 ch x 16 KB)
    //   ebuf: out4+12B,     8 MB (64 cb x 16 ch x  8 KB)
    //   candD f32 8 MB, candI ushort 4 MB after ebuf (fits out4+out5)
    ushort_t* zbuf = (ushort_t*)out0;
    unsigned char* s4 = (unsigned char*)out4 + 12;
    ushort_t* ebuf = (ushort_t*)s4;
    float* candD = (float*)(s4 + 8388608);
    ushort_t* candI = (ushort_t*)(s4 + 8388608 + 8388608);

    hipMemsetAsync(lossAcc, 0, sizeof(float), stream);

    k_split_z<<<(M_SZ * 64) / 256, 256, 0, stream>>>(z, zbuf);
    k_split_e<<<(K_SZ * 64) / 256, 256, 0, stream>>>(ew, ebuf, esq);

    k_pass1<<<4096, 512, 0, stream>>>(ebuf, zbuf, esq, candD, candI);
    k_refine<<<M_SZ / 4, 256, 0, stream>>>(z, ew, esq, candD, candI, nearest, out1);

    // now safe to overwrite scratch regions with real outputs
    k_initcopy<<<16384 + 8192, 256, 0, stream>>>(cb, sizes, z, out3, out4, out0);
    k_scatter<<<M_SZ / 8, 256, 0, stream>>>(z, ew, nearest, out3, out4, lossAcc);
    k_final<<<(K_SZ * D_SZ) / 256, 256, 0, stream>>>(out3, out4, out5, lossAcc, out2);
}

// Round 23
// 326.829 us; speedup vs baseline: 1.1592x; 1.1558x over previous
//
#include <hip/hip_runtime.h>
#include <cfloat>

// Problem constants
#define B_SZ 8
#define N_SZ 2048
#define D_SZ 512
#define K_SZ 8192
#define M_SZ (B_SZ * N_SZ)  // 16384

#define DECAY_F 0.99f
#define OMD_F ((float)(1.0 - 0.99))
#define EPS_F 1e-5f

// Output layout (flat float offsets, reference return order)
#define OUT1_OFF 8388608   // indices (B*N) as float
#define OUT2_OFF 8404992   // commitment loss (1)
#define OUT3_OFF 8404993   // new_ema_cluster_sizes (K)
#define OUT4_OFF 8413185   // new_ema_codebook (K*D)
#define OUT5_OFF 12607489  // new_embedding (K*D)

typedef unsigned short ushort_t;
typedef unsigned int uint_t;
typedef short bf16x8 __attribute__((ext_vector_type(8)));
typedef float f32x4 __attribute__((ext_vector_type(4)));

// ---- manual RTNE fp32 -> bf16 ----
__device__ inline ushort_t f2bf(float v) {
    union { float f; uint_t u; } x; x.f = v;
    uint_t r = x.u + 0x7FFFu + ((x.u >> 16) & 1u);
    return (ushort_t)(r >> 16);
}

// 16B global -> LDS DMA (linear per-lane dest; vmcnt-counted)
__device__ __forceinline__ void gl16(const void* g, void* l) {
    __builtin_amdgcn_global_load_lds(
        (const __attribute__((address_space(1))) uint_t*)g,
        (__attribute__((address_space(3))) uint_t*)l, 16, 0, 0);
}

// ------- splits: SINGLE bf16 plane, CHUNKED + PRE-SWIZZLED (BK=64) ----
// Chunk = 128 rows x 128B = 16384 B (R13-verified geometry):
//   byte[row*128 + ((kg^(row&7))<<4)] = bf16 of (row, k=ch*64+kg*8..+7)
// e chunks: (cb,ch) -> (cb*8+ch)*16384. z chunks: (zi,ch) -> same form.
// k_split_e also emits esq (row == 64 consecutive lanes -> free reduce).
__global__ __launch_bounds__(256) void k_split_e(const float* __restrict__ in,
                                                 ushort_t* __restrict__ ebuf,
                                                 float* __restrict__ esq) {
    int idx = blockIdx.x * 256 + threadIdx.x;
    int row = idx >> 6, o = idx & 63;       // o = k-octet 0..63
    int ch = o >> 3, kg = o & 7;
    const float* src = in + (size_t)row * D_SZ + o * 8;
    float4 a = *(const float4*)src;
    float4 b = *(const float4*)(src + 4);
    float vv[8] = {a.x, a.y, a.z, a.w, b.x, b.y, b.z, b.w};
    ushort_t o1[8];
    float s = 0.f;
#pragma unroll
    for (int j = 0; j < 8; ++j) {
        o1[j] = f2bf(vv[j]);
        s += vv[j] * vv[j];
    }
    int cb = row >> 7, rl = row & 127;
    size_t base = (size_t)(cb * 8 + ch) * 16384 + rl * 128;
    *(uint4*)((unsigned char*)ebuf + base + ((kg ^ (rl & 7)) << 4)) = *(uint4*)o1;
#pragma unroll
    for (int off = 32; off; off >>= 1) s += __shfl_down(s, off);
    if (o == 0) esq[row] = s;
}

__global__ __launch_bounds__(256) void k_split_z(const float* __restrict__ in,
                                                 ushort_t* __restrict__ zbuf) {
    int idx = blockIdx.x * 256 + threadIdx.x;
    int row = idx >> 6, o = idx & 63;
    int ch = o >> 3, kg = o & 7;
    const float* src = in + (size_t)row * D_SZ + o * 8;
    float4 a = *(const float4*)src;
    float4 b = *(const float4*)(src + 4);
    float vv[8] = {a.x, a.y, a.z, a.w, b.x, b.y, b.z, b.w};
    ushort_t o1[8];
#pragma unroll
    for (int j = 0; j < 8; ++j) o1[j] = f2bf(vv[j]);
    int zi = row >> 7, rl = row & 127;
    size_t base = (size_t)(zi * 8 + ch) * 16384 + rl * 128;
    *(uint4*)((unsigned char*)zbuf + base + ((kg ^ (rl & 7)) << 4)) = *(uint4*)o1;
}

// -------- fused init (out3/out4 scale) + copy (out0 = z) -------------
__global__ __launch_bounds__(256) void k_initcopy(const float* __restrict__ cb,
                                                  const float* __restrict__ sizes,
                                                  const float* __restrict__ z,
                                                  float* __restrict__ out3,
                                                  float* __restrict__ out4,
                                                  float* __restrict__ out0) {
    int b = blockIdx.x;
    if (b < 16384) {
        int i = b * 256 + threadIdx.x;
        out4[i] = cb[i] * DECAY_F;
        if (i < K_SZ) out3[i] = sizes[i] * DECAY_F;
    } else {
        int i = (b - 16384) * 256 + threadIdx.x;
        ((float4*)out0)[i] = ((const float4*)z)[i];
    }
}

__global__ __launch_bounds__(256) void k_scatter(const float* __restrict__ z,
                                                 const float* __restrict__ e,
                                                 const int* __restrict__ nearest,
                                                 float* __restrict__ out3,
                                                 float* __restrict__ out4,
                                                 float* __restrict__ lossAcc) {
    const int tid = threadIdx.x;
    float lp = 0.f;
    const int base_row = blockIdx.x * 8;
#pragma unroll
    for (int r = 0; r < 8; ++r) {
        int row = base_row + r;
        int n = nearest[row];
        float2 zv = ((const float2*)(z + (size_t)row * D_SZ))[tid];
        float2 ev = ((const float2*)(e + (size_t)n * D_SZ))[tid];
        float* o4 = out4 + (size_t)n * D_SZ + tid * 2;
        atomicAdd(o4, OMD_F * zv.x);
        atomicAdd(o4 + 1, OMD_F * zv.y);
        float dx = zv.x - ev.x, dy = zv.y - ev.y;
        lp += dx * dx + dy * dy;
        if (tid == 0) atomicAdd(out3 + n, OMD_F);
    }
#pragma unroll
    for (int off = 32; off; off >>= 1) lp += __shfl_down(lp, off);
    __shared__ float red[4];
    if ((tid & 63) == 0) red[tid >> 6] = lp;
    __syncthreads();
    if (tid == 0) atomicAdd(lossAcc, red[0] + red[1] + red[2] + red[3]);
}

__global__ __launch_bounds__(256) void k_final(const float* __restrict__ out3,
                                               const float* __restrict__ out4,
                                               float* __restrict__ out5,
                                               const float* __restrict__ lossAcc,
                                               float* __restrict__ out2) {
    int i = blockIdx.x * 256 + threadIdx.x;
    out5[i] = out4[i] / (out3[i >> 9] + EPS_F);
    if (i == 0) out2[0] = 0.25f * lossAcc[0] / 8388608.0f;
}

// ---------------- pass 1: single-plane bf16 MFMA + per-list top2 -----
// FINAL (R18 config, best verified: k_pass1 196 us, total 328 us).
// 16x16x32 MFMA, 128c x 128z tile, 512 thr = 8 waves (2mw x 4nw), wave
// tile 64c x 32z, BK=64, dbuf 64 KB. Unified-regfile model (session-
// measured): total = arch VGPR + MFMA-acc regs sets the wave tier;
// acc[4][2]=32 + 52 arch = 84 <= 128 -> 4 waves/SIMD. acc[4][4]-based
// ratio-2.0 variants (R19-R22) always exceed 128 -> 2 waves/SIMD and
// lose despite fewer LDS reads.
// Counted vmcnt (T4): ISSUE(t+1); vmcnt(4); barrier; compute(t);
// barrier — never drain to 0 in the loop.
// Swizzle kg^(row&7) on 128B rows: 0 conflicts (R8/R13/R18-verified).
// A/B frag (16x16x32): lane -> row=lr (lane&15), k=(lane>>4)*8+j.
// C/D: col=lane&15 (z), row=(lane>>4)*4+reg (code)  [m89/m91].
__global__ __launch_bounds__(512, 4) void k_pass1(const ushort_t* __restrict__ ebuf,
                                                  const ushort_t* __restrict__ zbuf,
                                                  const float* __restrict__ esq,
                                                  float* __restrict__ candD,
                                                  ushort_t* __restrict__ candI) {
    __shared__ __align__(16) unsigned char ldsb[65536];  // 2 x (16K e + 16K z)

    const int tid = threadIdx.x;
    const int lane = tid & 63;
    const int wv = tid >> 6;            // 0..7
    const int mw = wv >> 2;             // 0..1 (code wave-half)
    const int nw = wv & 3;              // 0..3 (z wave-quarter)
    const int lr = lane & 15;           // frag row
    const int g = lane >> 4;            // k-group / D row-group

    // XCD pinning: blockIdx&7 = XCD = cb>>3 -> each XCD owns a 1024-code
    // e-slice (1 MB single-plane) resident in its L2.
    const int xcd = blockIdx.x & 7;
    const int cbl = (blockIdx.x >> 3) & 7;
    const int zi = blockIdx.x >> 6;     // 0..127
    const int cb = xcd * 8 + cbl;       // 0..63

    const unsigned char* esrc = (const unsigned char*)ebuf + (size_t)cb * 131072 + tid * 16;
    const unsigned char* zsrc = (const unsigned char*)zbuf + (size_t)zi * 131072 + tid * 16;

#define ISSUE(c, b) do {                                                \
        const unsigned char* ep_ = esrc + (c) * 16384;                  \
        const unsigned char* zp_ = zsrc + (c) * 16384;                  \
        unsigned char* el_ = ldsb + (b) * 32768 + tid * 16;             \
        unsigned char* zl_ = el_ + 16384;                               \
        gl16(ep_, el_); gl16(ep_ + 8192, el_ + 8192);                   \
        gl16(zp_, zl_); gl16(zp_ + 8192, zl_ + 8192);                   \
    } while (0)

    f32x4 acc[4][2];
#pragma unroll
    for (int mf = 0; mf < 4; ++mf)
#pragma unroll
        for (int nf = 0; nf < 2; ++nf)
            acc[mf][nf] = (f32x4){0.f, 0.f, 0.f, 0.f};

    // prologue: chunk 0 -> buf 0 (wait happens inside the loop)
    ISSUE(0, 0);

    int cur = 0;
    for (int ch = 0; ch < 8; ++ch) {
        // issue-early: next chunk -> other buffer, then wait ONLY for
        // chunk ch's 4 loads (the 4 newest outstanding are ch+1's).
        if (ch < 7) {
            if (cur) ISSUE(ch + 1, 0); else ISSUE(ch + 1, 1);
            asm volatile("s_waitcnt vmcnt(4)" ::: "memory");
        } else {
            asm volatile("s_waitcnt vmcnt(0)" ::: "memory");
        }
        __builtin_amdgcn_s_barrier();   // all waves' chunk-ch loads landed
        asm volatile("" ::: "memory");

        const unsigned char* eb = ldsb + cur * 32768;
        const unsigned char* zp = eb + 16384;

#pragma unroll
        for (int ks = 0; ks < 2; ++ks) {      // two k=32 halves of BK=64
            bf16x8 zf[2];
#pragma unroll
            for (int nf = 0; nf < 2; ++nf) {
                int row = nw * 32 + nf * 16 + lr;
                int sl = (ks * 4 + g) ^ (row & 7);
                zf[nf] = *(const bf16x8*)(zp + row * 128 + (sl << 4));
            }
#pragma unroll
            for (int mf = 0; mf < 4; ++mf) {
                int row = mw * 64 + mf * 16 + lr;
                int sl = (ks * 4 + g) ^ (row & 7);
                bf16x8 ef = *(const bf16x8*)(eb + row * 128 + (sl << 4));
#pragma unroll
                for (int nf = 0; nf < 2; ++nf)
                    acc[mf][nf] = __builtin_amdgcn_mfma_f32_16x16x32_bf16(ef, zf[nf], acc[mf][nf], 0, 0, 0);
            }
        }
        // all waves done reading buf before next ISSUE overwrites it
        __builtin_amdgcn_s_barrier();
        asm volatile("" ::: "memory");
        cur ^= 1;
    }
#undef ISSUE

    // epilogue: dist = esq - 2*dot; per-zrow top2 over this wave's 64 codes
    float b1[2], b2[2];
    int i1[2], i2[2];
#pragma unroll
    for (int nf = 0; nf < 2; ++nf) {
        b1[nf] = FLT_MAX; b2[nf] = FLT_MAX;
        i1[nf] = 0x7fffffff; i2[nf] = 0x7fffffff;
    }
    const int code0 = cb * 128 + mw * 64;
#pragma unroll
    for (int mf = 0; mf < 4; ++mf)
#pragma unroll
        for (int r = 0; r < 4; ++r) {
            int code = code0 + mf * 16 + g * 4 + r;
            float eq = esq[code];
#pragma unroll
            for (int nf = 0; nf < 2; ++nf) {
                float d = fmaf(-2.f, acc[mf][nf][r], eq);
                if (d < b1[nf]) {
                    b2[nf] = b1[nf]; i2[nf] = i1[nf];
                    b1[nf] = d; i1[nf] = code;
                } else if (d < b2[nf]) {
                    b2[nf] = d; i2[nf] = code;
                }
            }
        }

    // merge top2 across the 4 k-groups holding the same zrow (xor 16, 32)
#pragma unroll
    for (int off = 16; off <= 32; off <<= 1) {
#pragma unroll
        for (int nf = 0; nf < 2; ++nf) {
            float ob1 = __shfl_xor(b1[nf], off); int oi1 = __shfl_xor(i1[nf], off);
            float ob2 = __shfl_xor(b2[nf], off); int oi2 = __shfl_xor(i2[nf], off);
            bool tA = (b1[nf] < ob1) || (b1[nf] == ob1 && i1[nf] <= oi1);
            float n1 = tA ? b1[nf] : ob1; int ni1 = tA ? i1[nf] : oi1;
            float ca = tA ? b2[nf] : ob2; int cia = tA ? i2[nf] : oi2;
            float cbv = tA ? ob1 : b1[nf]; int cib = tA ? oi1 : i1[nf];
            bool t2 = (ca < cbv) || (ca == cbv && cia <= cib);
            b1[nf] = n1; i1[nf] = ni1;
            b2[nf] = t2 ? ca : cbv; i2[nf] = t2 ? cia : cib;
        }
    }

    // cross-wave merge (mw=0 vs mw=1 cover the same zrows) via LDS reuse
    __syncthreads();
    float* mD = (float*)ldsb;          // [128][2]
    int* mI = (int*)(ldsb + 1024);     // [128][2]
    if (mw == 1 && g == 0) {
#pragma unroll
        for (int nf = 0; nf < 2; ++nf) {
            int zr = nw * 32 + nf * 16 + lr;
            mD[zr * 2] = b1[nf]; mD[zr * 2 + 1] = b2[nf];
            mI[zr * 2] = i1[nf]; mI[zr * 2 + 1] = i2[nf];
        }
    }
    __syncthreads();
    if (mw == 0 && g == 0) {
#pragma unroll
        for (int nf = 0; nf < 2; ++nf) {
            int zr = nw * 32 + nf * 16 + lr;
            float ob1 = mD[zr * 2], ob2 = mD[zr * 2 + 1];
            int oi1 = mI[zr * 2], oi2 = mI[zr * 2 + 1];
            bool tA = (b1[nf] < ob1) || (b1[nf] == ob1 && i1[nf] <= oi1);
            float n1 = tA ? b1[nf] : ob1; int ni1 = tA ? i1[nf] : oi1;
            float ca = tA ? b2[nf] : ob2; int cia = tA ? i2[nf] : oi2;
            float cbv = tA ? ob1 : b1[nf]; int cib = tA ? oi1 : i1[nf];
            bool t2 = (ca < cbv) || (ca == cbv && cia <= cib);
            float n2 = t2 ? ca : cbv; int ni2 = t2 ? cia : cib;
            int row = zi * 128 + zr;
            size_t base = (size_t)row * 128 + cb * 2;
            candD[base] = n1; candD[base + 1] = n2;
            candI[base] = (ushort_t)ni1; candI[base + 1] = (ushort_t)ni2;
        }
    }
}

// ---------------- refine: exact fp32 re-rank of merged top-8 ---------
// 128 candidates/row (top-2 x 64 lists); extract 8 approx-minima, exact
// fp32 re-rank (same expression as verified R5-R18 refine).
__global__ __launch_bounds__(256) void k_refine(const float* __restrict__ z,
                                                const float* __restrict__ e,
                                                const float* __restrict__ esq,
                                                const float* __restrict__ candD,
                                                const ushort_t* __restrict__ candI,
                                                int* __restrict__ nearest,
                                                float* __restrict__ out1) {
    const int lane = threadIdx.x & 63;
    const int row = blockIdx.x * 4 + (threadIdx.x >> 6);

    const float4* zr = (const float4*)(z + (size_t)row * D_SZ + lane * 8);
    float4 za = zr[0], zb = zr[1];
    float zsq = za.x * za.x + za.y * za.y + za.z * za.z + za.w * za.w +
                zb.x * zb.x + zb.y * zb.y + zb.z * zb.z + zb.w * zb.w;
#pragma unroll
    for (int off = 32; off; off >>= 1) zsq += __shfl_xor(zsq, off);

    float da = candD[(size_t)row * 128 + lane];
    int ia = candI[(size_t)row * 128 + lane];
    float db = candD[(size_t)row * 128 + 64 + lane];
    int ib = candI[(size_t)row * 128 + 64 + lane];

    float best = FLT_MAX;
    int bidx = 0x7fffffff;
#pragma unroll
    for (int c = 0; c < 8; ++c) {
        bool pa = (da < db) || (da == db && ia < ib);
        float md = pa ? da : db;
        int mi = pa ? ia : ib;
#pragma unroll
        for (int off = 32; off; off >>= 1) {
            float od = __shfl_xor(md, off); int oi = __shfl_xor(mi, off);
            if (od < md || (od == md && oi < mi)) { md = od; mi = oi; }
        }
        if (ia == mi) da = FLT_MAX;  // codes unique across all 128 cands
        if (ib == mi) db = FLT_MAX;
        // exact fp32 distance for candidate mi
        const float4* er = (const float4*)(e + (size_t)mi * D_SZ + lane * 8);
        float4 ea = er[0], eb = er[1];
        float dot = za.x * ea.x + za.y * ea.y + za.z * ea.z + za.w * ea.w +
                    zb.x * eb.x + zb.y * eb.y + zb.z * eb.z + zb.w * eb.w;
#pragma unroll
        for (int off = 32; off; off >>= 1) dot += __shfl_xor(dot, off);
        float dex = (zsq - 2.f * dot) + esq[mi];
        if (dex < best || (dex == best && mi < bidx)) { best = dex; bidx = mi; }
    }
    if (lane == 0) {
        nearest[row] = bidx;
        out1[row] = (float)bidx;
    }
}

extern "C" void kernel_launch(void* const* d_in, const int* in_sizes, int n_in,
                              void* d_out, int out_size, void* d_ws, size_t ws_size,
                              hipStream_t stream) {
    const float* z = (const float*)d_in[0];
    const float* ew = (const float*)d_in[1];
    const float* sizes = (const float*)d_in[2];
    const float* cb = (const float*)d_in[3];

    float* out = (float*)d_out;
    float* out0 = out;
    float* out1 = out + OUT1_OFF;
    float* out2 = out + OUT2_OFF;
    float* out3 = out + OUT3_OFF;
    float* out4 = out + OUT4_OFF;
    float* out5 = out + OUT5_OFF;

    // ws scratch (small)
    int* nearest = (int*)d_ws;
    float* esq = (float*)d_ws + M_SZ;
    float* lossAcc = (float*)d_ws + M_SZ + K_SZ;

    // chunked/pre-swizzled single-plane buffers inside d_out (consumed
    // before the real outputs overwrite them):
    //   zbuf: out0 region, 16 MB (128 zi x 8 ch x 16 KB)
    //   ebuf: out4+12B,     8 MB ( 64 cb x 8 ch x 16 KB)
    //   candD f32 8 MB, candI ushort 4 MB after ebuf (fits out4+out5)
    ushort_t* zbuf = (ushort_t*)out0;
    unsigned char* s4 = (unsigned char*)out4 + 12;
    ushort_t* ebuf = (ushort_t*)s4;
    float* candD = (float*)(s4 + 8388608);
    ushort_t* candI = (ushort_t*)(s4 + 8388608 + 8388608);

    hipMemsetAsync(lossAcc, 0, sizeof(float), stream);

    k_split_z<<<(M_SZ * 64) / 256, 256, 0, stream>>>(z, zbuf);
    k_split_e<<<(K_SZ * 64) / 256, 256, 0, stream>>>(ew, ebuf, esq);

    k_pass1<<<8192, 512, 0, stream>>>(ebuf, zbuf, esq, candD, candI);
    k_refine<<<M_SZ / 4, 256, 0, stream>>>(z, ew, esq, candD, candI, nearest, out1);

    // now safe to overwrite scratch regions with real outputs
    k_initcopy<<<16384 + 8192, 256, 0, stream>>>(cb, sizes, z, out3, out4, out0);
    k_scatter<<<M_SZ / 8, 256, 0, stream>>>(z, ew, nearest, out3, out4, lossAcc);
    k_final<<<(K_SZ * D_SZ) / 256, 256, 0, stream>>>(out3, out4, out5, lossAcc, out2);
}